// Round 1
// baseline (369.965 us; speedup 1.0000x reference)
//
#include <hip/hip_runtime.h>

#define HH 512
#define WW 512
#define NB 8
#define NN 32

// ---------------------------------------------------------------------------
// Kernel A: per-row min/max column index of positive pixels in seg[...,1].
// One wave per row; lanes stride columns; float2 load grabs (ch0,ch1) pairs.
// ---------------------------------------------------------------------------
__global__ __launch_bounds__(256) void rowminmax_kernel(
    const float* __restrict__ seg, int* __restrict__ xmin, int* __restrict__ xmax) {
  int wv = threadIdx.x >> 6;
  int lane = threadIdx.x & 63;
  int g = blockIdx.x * 4 + wv;                 // global row id in [0, NB*HH)
  const float2* row = ((const float2*)seg) + (size_t)g * WW;
  int mn = WW, mx = -1;
#pragma unroll
  for (int k = 0; k < WW / 64; ++k) {
    int w = lane + k * 64;
    float v = row[w].y;                        // channel 1
    if (v > 0.0f) { if (w < mn) mn = w; if (w > mx) mx = w; }
  }
  for (int off = 32; off; off >>= 1) {
    int omn = __shfl_down(mn, off);
    int omx = __shfl_down(mx, off);
    mn = min(mn, omn);
    mx = max(mx, omx);
  }
  if (lane == 0) { xmin[g] = mn; xmax[g] = mx; }
}

// ---------------------------------------------------------------------------
// Kernel B: per-batch weighted least-squares fit -> unit[h] = 3.25 / width[h].
// One block per batch, thread t == row t. Matches reference semantics:
//   valid, rank = inclusive_cumsum(valid)-1, drop = max(1,(int)(n_valid*0.15f)),
//   keep window, normal equations (double accum), clip width at 1.0.
// ---------------------------------------------------------------------------
__global__ __launch_bounds__(512) void fit_kernel(
    const int* __restrict__ xmin, const int* __restrict__ xmax,
    float* __restrict__ unit, float* __restrict__ unit2) {
  int b = blockIdx.x;
  int t = threadIdx.x;                         // row index
  int wv = t >> 6, lane = t & 63;
  __shared__ int s_scan[HH];
  __shared__ double s_red[8][8];               // [wave][7 sums] (padded)
  __shared__ double s_fit[4];

  int xmn = xmin[b * HH + t];
  int xmx = xmax[b * HH + t];
  int valid = (xmx >= 0 && xmn != xmx) ? 1 : 0;
  s_scan[t] = valid;
  __syncthreads();
  // Hillis-Steele inclusive scan over 512 flags
  for (int off = 1; off < HH; off <<= 1) {
    int add = (t >= off) ? s_scan[t - off] : 0;
    __syncthreads();
    s_scan[t] += add;
    __syncthreads();
  }
  int n_valid = s_scan[HH - 1];
  int rank = s_scan[t] - 1;
  int drop = (int)((float)n_valid * 0.15f);    // same f32 truncation as reference
  if (drop < 1) drop = 1;
  int keep = (valid && rank >= drop && rank < (n_valid - drop)) ? 1 : 0;

  double wg = (double)keep;
  double y  = (double)t;
  double xl = (double)xmn, xr = (double)xmx;
  double terms[7];
  terms[0] = wg;        terms[1] = wg * y;      terms[2] = wg * y * y;
  terms[3] = wg * xl;   terms[4] = wg * y * xl;
  terms[5] = wg * xr;   terms[6] = wg * y * xr;
#pragma unroll
  for (int i = 0; i < 7; ++i) {
    double v = terms[i];
    for (int off = 32; off; off >>= 1) v += __shfl_down(v, off);
    if (lane == 0) s_red[wv][i] = v;
  }
  __syncthreads();
  if (t == 0) {
    double S[7];
    for (int i = 0; i < 7; ++i) {
      double a = 0.0;
      for (int w2 = 0; w2 < 8; ++w2) a += s_red[w2][i];
      S[i] = a;
    }
    double Sw = S[0], Sy = S[1], Syy = S[2];
    double Sxl = S[3], Sxyl = S[4], Sxr = S[5], Sxyr = S[6];
    double det = Syy * Sw - Sy * Sy;
    double sl_l = 0, ic_l = 0, sl_r = 0, ic_r = 0;
    if (det > 0.0) {
      sl_l = (Sw * Sxyl - Sy * Sxl) / det;
      ic_l = (-Sy * Sxyl + Syy * Sxl) / det;
      sl_r = (Sw * Sxyr - Sy * Sxr) / det;
      ic_r = (-Sy * Sxyr + Syy * Sxr) / det;
    }
    s_fit[0] = sl_l; s_fit[1] = ic_l; s_fit[2] = sl_r; s_fit[3] = ic_r;
  }
  __syncthreads();
  double pl = y * s_fit[0] + s_fit[1];
  double pr = y * s_fit[2] + s_fit[3];
  double wdt = pr - pl;
  if (wdt < 1.0) wdt = 1.0;
  float u = (float)(3.25 / wdt);
  unit[b * HH + t]  = u;
  unit2[b * HH + t] = u * u;
}

// ---------------------------------------------------------------------------
// Kernel C: the 256 MB streaming reduction. One block per (b,n); thread t
// owns column w=t so each h-iteration is one coalesced 2KB block read.
// Unroll 8 for memory-level parallelism. occ[h] via per-wave ballot +
// benign same-value LDS store.
// ---------------------------------------------------------------------------
__global__ __launch_bounds__(512) void reduce_kernel(
    const float* __restrict__ pad, const float* __restrict__ unit,
    const float* __restrict__ unit2, float* __restrict__ out) {
  int bn = blockIdx.x;                         // 0..255
  int b = bn >> 5;                             // N = 32
  int t = threadIdx.x;                         // column
  int wv = t >> 6, lane = t & 63;
  __shared__ float s_u[HH], s_u2[HH];
  __shared__ unsigned int s_occ[HH];
  __shared__ float s_tmp[3][8];

  s_u[t]  = unit[b * HH + t];
  s_u2[t] = unit2[b * HH + t];
  s_occ[t] = 0u;
  __syncthreads();

  const float* p = pad + (size_t)bn * (HH * WW) + t;
  float colsum = 0.0f, inst = 0.0f;
  for (int h0 = 0; h0 < HH; h0 += 8) {
    float v[8];
#pragma unroll
    for (int k = 0; k < 8; ++k) v[k] = p[(size_t)(h0 + k) * WW];
#pragma unroll
    for (int k = 0; k < 8; ++k) {
      int h = h0 + k;
      colsum = fmaf(s_u[h],  v[k], colsum);
      inst   = fmaf(s_u2[h], v[k], inst);
      unsigned long long any = __ballot(v[k] > 0.5f);
      if (any && lane == 0) s_occ[h] = 1u;     // same-value store: race-benign
    }
  }
  __syncthreads();

  float vt = s_occ[t] ? s_u[t] : 0.0f;         // thread t == row t here
  float si = inst, sv = vt, mc = colsum;
  for (int off = 32; off; off >>= 1) {
    si += __shfl_down(si, off);
    sv += __shfl_down(sv, off);
    float o = __shfl_down(mc, off);
    mc = fmaxf(mc, o);
  }
  if (lane == 0) { s_tmp[0][wv] = si; s_tmp[1][wv] = mc; s_tmp[2][wv] = sv; }
  __syncthreads();
  if (t == 0) {
    float a = 0.0f, m = -1e30f, vs = 0.0f;
    for (int i = 0; i < 8; ++i) {
      a += s_tmp[0][i];
      m = fmaxf(m, s_tmp[1][i]);
      vs += s_tmp[2][i];
    }
    out[bn * 3 + 0] = a;   // instance_size
    out[bn * 3 + 1] = m;   // horizontal_size
    out[bn * 3 + 2] = vs;  // vertical_size
  }
}

extern "C" void kernel_launch(void* const* d_in, const int* in_sizes, int n_in,
                              void* d_out, int out_size, void* d_ws, size_t ws_size,
                              hipStream_t stream) {
  const float* seg = (const float*)d_in[0];    // [B,H,W,2]
  const float* pad = (const float*)d_in[1];    // [B,N,H,W]
  float* out = (float*)d_out;                  // [B,N,3]
  char* ws = (char*)d_ws;
  int*   xmin  = (int*)(ws);                   // 16 KB
  int*   xmax  = (int*)(ws + 16 * 1024);       // 16 KB
  float* unit  = (float*)(ws + 32 * 1024);     // 16 KB
  float* unit2 = (float*)(ws + 48 * 1024);     // 16 KB

  rowminmax_kernel<<<NB * HH / 4, 256, 0, stream>>>(seg, xmin, xmax);
  fit_kernel<<<NB, 512, 0, stream>>>(xmin, xmax, unit, unit2);
  reduce_kernel<<<NB * NN, 512, 0, stream>>>(pad, unit, unit2, out);
}